// Round 16
// baseline (104.669 us; speedup 1.0000x reference)
//
#include <hip/hip_runtime.h>
#include <math.h>

#define Bb 8
#define Nn 2048
#define ALPHA 0.2f
#define LN_EPS 1e-5f
#define LOG2E 1.4426950408889634f

typedef __attribute__((ext_vector_type(8))) short short8;
typedef __attribute__((ext_vector_type(4))) float f32x4;
typedef __attribute__((ext_vector_type(4))) int int4v;

__device__ inline unsigned short f2bf(float f) {
    unsigned u = __builtin_bit_cast(unsigned, f);
    u += 0x7fffu + ((u >> 16) & 1u);   // RNE
    return (unsigned short)(u >> 16);
}

__device__ __forceinline__ void gll16(const void* g, void* l) {
    __builtin_amdgcn_global_load_lds(
        (const __attribute__((address_space(1))) unsigned int*)g,
        (__attribute__((address_space(3))) unsigned int*)l, 16, 0, 0);
}

// ---- Kernel 1: PREP = pack_mask (blocks 0..2047) + node_transform_mfma ----
// REP: idempotent re-execution for measurement.
template <int REP>
__global__ __launch_bounds__(256) void prep(
    const int* __restrict__ adj,
    const float* __restrict__ in, const float* __restrict__ W,
    const float* __restrict__ a, const float* __restrict__ nw,
    const float* __restrict__ nb, const float* __restrict__ gam,
    const float* __restrict__ bet,
    unsigned int* __restrict__ bitsT,
    float* __restrict__ h, float* __restrict__ s1L, float* __restrict__ s2L,
    unsigned short* __restrict__ hT2)
{
    __shared__ unsigned char rowb[256];
    int bid = blockIdx.x, t = threadIdx.x;

    if (bid < Nn) {
        for (int rep = 0; rep < REP; ++rep) {
            int i = bid;
            const int4* arow = (const int4*)(adj + (size_t)i * Nn);
            int4 v0 = arow[t * 2], v1 = arow[t * 2 + 1];
            unsigned by = (unsigned)(v0.x > 0)       | ((unsigned)(v0.y > 0) << 1)
                        | ((unsigned)(v0.z > 0) << 2) | ((unsigned)(v0.w > 0) << 3)
                        | ((unsigned)(v1.x > 0) << 4) | ((unsigned)(v1.y > 0) << 5)
                        | ((unsigned)(v1.z > 0) << 6) | ((unsigned)(v1.w > 0) << 7);
            rowb[t] = (unsigned char)by;
            __syncthreads();
            if (t < 64) {
                unsigned w32;
                __builtin_memcpy(&w32, &rowb[t * 4], 4);
                bitsT[((size_t)(i >> 4) * 64 + t) * 16 + (i & 15)] = w32;
            }
            __syncthreads();
        }
        return;
    }

    int lane = t & 63, wv = t >> 6;
    int am = lane & 15, ag = lane >> 4;
    int node0 = (bid - Nn) * 64 + wv * 16;
    int b = node0 >> 11;
    int n0 = node0 & (Nn - 1);

    for (int rep = 0; rep < REP; ++rep) {
        short8 wf[4][2];
#pragma unroll
        for (int cb = 0; cb < 4; ++cb)
#pragma unroll
            for (int kh = 0; kh < 2; ++kh)
#pragma unroll
                for (int e = 0; e < 8; ++e)
                    wf[cb][kh][e] = (short)f2bf(W[(kh * 32 + 8 * ag + e) * 64 + cb * 16 + am]);

        int nrow = n0 + am;
        float nwv = nw[nrow] + 1.0f, nbv = nb[nrow];
        const float* xrow = in + (size_t)(node0 + am) * 64 + 8 * ag;
        short8 xa0, xa1;
#pragma unroll
        for (int e = 0; e < 8; ++e) {
            xa0[e] = (short)f2bf(xrow[e] * nwv + nbv);
            xa1[e] = (short)f2bf(xrow[32 + e] * nwv + nbv);
        }

        f32x4 acc0 = {0,0,0,0}, acc1 = {0,0,0,0}, acc2 = {0,0,0,0}, acc3 = {0,0,0,0};
        acc0 = __builtin_amdgcn_mfma_f32_16x16x32_bf16(xa0, wf[0][0], acc0, 0, 0, 0);
        acc1 = __builtin_amdgcn_mfma_f32_16x16x32_bf16(xa0, wf[1][0], acc1, 0, 0, 0);
        acc2 = __builtin_amdgcn_mfma_f32_16x16x32_bf16(xa0, wf[2][0], acc2, 0, 0, 0);
        acc3 = __builtin_amdgcn_mfma_f32_16x16x32_bf16(xa0, wf[3][0], acc3, 0, 0, 0);
        acc0 = __builtin_amdgcn_mfma_f32_16x16x32_bf16(xa1, wf[0][1], acc0, 0, 0, 0);
        acc1 = __builtin_amdgcn_mfma_f32_16x16x32_bf16(xa1, wf[1][1], acc1, 0, 0, 0);
        acc2 = __builtin_amdgcn_mfma_f32_16x16x32_bf16(xa1, wf[2][1], acc2, 0, 0, 0);
        acc3 = __builtin_amdgcn_mfma_f32_16x16x32_bf16(xa1, wf[3][1], acc3, 0, 0, 0);

        float mu[4], rsq[4];
#pragma unroll
        for (int q = 0; q < 4; ++q) {
            float s = (acc0[q] + acc1[q]) + (acc2[q] + acc3[q]);
            s += __shfl_xor(s, 1, 64); s += __shfl_xor(s, 2, 64);
            s += __shfl_xor(s, 4, 64); s += __shfl_xor(s, 8, 64);
            mu[q] = s * (1.f / 64.f);
        }
#pragma unroll
        for (int q = 0; q < 4; ++q) {
            float d0 = acc0[q] - mu[q], d1 = acc1[q] - mu[q];
            float d2 = acc2[q] - mu[q], d3 = acc3[q] - mu[q];
            float ss = (d0 * d0 + d1 * d1) + (d2 * d2 + d3 * d3);
            ss += __shfl_xor(ss, 1, 64); ss += __shfl_xor(ss, 2, 64);
            ss += __shfl_xor(ss, 4, 64); ss += __shfl_xor(ss, 8, 64);
            rsq[q] = rsqrtf(ss * (1.f / 64.f) + LN_EPS);
        }
        float gl0 = gam[am], gl1 = gam[16 + am], gl2 = gam[32 + am], gl3 = gam[48 + am];
        float bl0 = bet[am], bl1 = bet[16 + am], bl2 = bet[32 + am], bl3 = bet[48 + am];
        f32x4 hn0, hn1, hn2, hn3;
#pragma unroll
        for (int q = 0; q < 4; ++q) {
            hn0[q] = (acc0[q] - mu[q]) * rsq[q] * gl0 + bl0;
            hn1[q] = (acc1[q] - mu[q]) * rsq[q] * gl1 + bl1;
            hn2[q] = (acc2[q] - mu[q]) * rsq[q] * gl2 + bl2;
            hn3[q] = (acc3[q] - mu[q]) * rsq[q] * gl3 + bl3;
        }

        float a10 = a[am], a11 = a[16 + am], a12 = a[32 + am], a13 = a[48 + am];
        float a20 = a[64 + am], a21 = a[80 + am], a22 = a[96 + am], a23 = a[112 + am];
        float s1p[4], s2p[4];
#pragma unroll
        for (int q = 0; q < 4; ++q) {
            float s1v = (hn0[q] * a10 + hn1[q] * a11) + (hn2[q] * a12 + hn3[q] * a13);
            float s2v = (hn0[q] * a20 + hn1[q] * a21) + (hn2[q] * a22 + hn3[q] * a23);
            s1v += __shfl_xor(s1v, 1, 64); s1v += __shfl_xor(s1v, 2, 64);
            s1v += __shfl_xor(s1v, 4, 64); s1v += __shfl_xor(s1v, 8, 64);
            s2v += __shfl_xor(s2v, 1, 64); s2v += __shfl_xor(s2v, 2, 64);
            s2v += __shfl_xor(s2v, 4, 64); s2v += __shfl_xor(s2v, 8, 64);
            s1p[q] = s1v; s2p[q] = s2v;
        }
        if (am == 0) {
#pragma unroll
            for (int q = 0; q < 4; ++q) {
                s1L[node0 + ag * 4 + q] = s1p[q] * LOG2E;
                s2L[node0 + ag * 4 + q] = s2p[q] * LOG2E;
            }
        }

#pragma unroll
        for (int q = 0; q < 4; ++q) {
            float* hp = h + (size_t)(node0 + ag * 4 + q) * 64 + am;
            hp[0] = hn0[q]; hp[16] = hn1[q]; hp[32] = hn2[q]; hp[48] = hn3[q];
        }

        int jw = n0 >> 5;
        int AG2 = ((n0 & 31) >> 3) + (ag >> 1);
        int e0 = (ag & 1) * 4;
        size_t fbase = ((size_t)((b * 64 + jw) * 4)) * 512 + (AG2 * 16 + am) * 8 + e0;
#pragma unroll
        for (int cb = 0; cb < 4; ++cb) {
            f32x4 hc = cb == 0 ? hn0 : cb == 1 ? hn1 : cb == 2 ? hn2 : hn3;
            unsigned short v[4] = {f2bf(hc[0]), f2bf(hc[1]), f2bf(hc[2]), f2bf(hc[3])};
            *(uint2*)&hT2[fbase + (size_t)cb * 512] = *(uint2*)v;
        }
    }
}

// ---- Kernel 2: full-j attention (r14 ring-2 structure), REP'd --------------
// grid (64, 8) = 512 blocks, 48 KB LDS. 4 waves: rr = wv&1, js = wv>>1.
template <int REP>
__global__ __launch_bounds__(256) void attention9(
    const float* __restrict__ h, const unsigned short* __restrict__ hT2,
    const float* __restrict__ s1L, const float* __restrict__ s2L,
    const unsigned int* __restrict__ bitsT, float* __restrict__ out)
{
    __shared__ __align__(16) unsigned short frag[2][4][4][512];  // 32 KB ring
    __shared__ __align__(16) unsigned int mask_lds[2][64][16];   // 8 KB
    __shared__ __align__(16) float s2l[2048];                    // 8 KB

    int t = threadIdx.x, wv = t >> 6, lane = t & 63;
    int am = lane & 15, ag = lane >> 4;
    int rr = wv & 1, js = wv >> 1;
    int bx = blockIdx.x, b = blockIdx.y;

    float s1r = s1L[b * Nn + bx * 32 + rr * 16 + am];
    const unsigned int* msrc = bitsT + (size_t)(bx * 2) * 1024;
    const float* ssrc = s2L + b * Nn;
    const unsigned short* slab = hT2 + (size_t)b * 131072;

    // mask + s2 staged once (not clobbered by reps)
#pragma unroll
    for (int k = 0; k < 2; ++k) {
        int sl = wv * 2 + k;
        gll16(msrc + sl * 256 + lane * 4, &((unsigned int*)mask_lds)[sl * 256]);
        gll16(ssrc + sl * 256 + lane * 4, &s2l[sl * 256]);
    }
    asm volatile("s_waitcnt vmcnt(0)" ::: "memory");
    __builtin_amdgcn_s_barrier();

    const short8 vone = {(short)0x3F80, (short)0x3F80, (short)0x3F80, (short)0x3F80,
                         (short)0x3F80, (short)0x3F80, (short)0x3F80, (short)0x3F80};

    for (int rep = 0; rep < REP; ++rep) {
        __syncthreads();   // prev rep's epilogue readers done; frag reusable

        // stage 0 (words 0..3): wave wv stages word wv, 4 fb slices
#pragma unroll
        for (int fb = 0; fb < 4; ++fb)
            gll16(slab + (size_t)(wv * 4 + fb) * 512 + lane * 8, &frag[0][wv][fb][0]);
        asm volatile("s_waitcnt vmcnt(0)" ::: "memory");
        __builtin_amdgcn_s_barrier();

        f32x4 acc0 = {0,0,0,0}, acc1 = {0,0,0,0}, acc2 = {0,0,0,0}, acc3 = {0,0,0,0};
        f32x4 accz = {0,0,0,0};

#pragma unroll
        for (int st = 0; st < 16; ++st) {
            if (st < 15) {                                   // prefetch next stage
                int gw = (st + 1) * 4 + wv;
#pragma unroll
                for (int fb = 0; fb < 4; ++fb)
                    gll16(slab + (size_t)(gw * 4 + fb) * 512 + lane * 8,
                          &frag[(st + 1) & 1][wv][fb][0]);
            }
#pragma unroll
            for (int wi = 0; wi < 2; ++wi) {
                int wls = js * 2 + wi;                       // stage-local word
                int wl = st * 4 + wls;                       // global word
                unsigned wd = mask_lds[rr][wl][am];
                float4 sa = *(const float4*)&s2l[wl * 32 + 8 * ag];
                float4 sb = *(const float4*)&s2l[wl * 32 + 8 * ag + 4];
                float se[8] = {sa.x, sa.y, sa.z, sa.w, sb.x, sb.y, sb.z, sb.w};
                float p[8];
#pragma unroll
                for (int e = 0; e < 8; ++e) {
                    float x = s1r + se[e];
                    float lr = fmaxf(x, ALPHA * x);
                    float ev = __builtin_amdgcn_exp2f(lr);
                    p[e] = ((wd >> (8 * ag + e)) & 1u) ? ev : 0.f;
                }
                int4v aw;
                aw.x = __builtin_amdgcn_perm(__builtin_bit_cast(unsigned, p[1]),
                                             __builtin_bit_cast(unsigned, p[0]), 0x07060302u);
                aw.y = __builtin_amdgcn_perm(__builtin_bit_cast(unsigned, p[3]),
                                             __builtin_bit_cast(unsigned, p[2]), 0x07060302u);
                aw.z = __builtin_amdgcn_perm(__builtin_bit_cast(unsigned, p[5]),
                                             __builtin_bit_cast(unsigned, p[4]), 0x07060302u);
                aw.w = __builtin_amdgcn_perm(__builtin_bit_cast(unsigned, p[7]),
                                             __builtin_bit_cast(unsigned, p[6]), 0x07060302u);
                short8 af = __builtin_bit_cast(short8, aw);
                short8 f0 = *(const short8*)&frag[st & 1][wls][0][lane * 8];
                short8 f1 = *(const short8*)&frag[st & 1][wls][1][lane * 8];
                short8 f2 = *(const short8*)&frag[st & 1][wls][2][lane * 8];
                short8 f3 = *(const short8*)&frag[st & 1][wls][3][lane * 8];
                acc0 = __builtin_amdgcn_mfma_f32_16x16x32_bf16(af, f0, acc0, 0, 0, 0);
                acc1 = __builtin_amdgcn_mfma_f32_16x16x32_bf16(af, f1, acc1, 0, 0, 0);
                acc2 = __builtin_amdgcn_mfma_f32_16x16x32_bf16(af, f2, acc2, 0, 0, 0);
                acc3 = __builtin_amdgcn_mfma_f32_16x16x32_bf16(af, f3, acc3, 0, 0, 0);
                accz = __builtin_amdgcn_mfma_f32_16x16x32_bf16(af, vone, accz, 0, 0, 0);
            }
            asm volatile("s_waitcnt vmcnt(0)" ::: "memory");
            __builtin_amdgcn_s_barrier();
        }

        // epilogue: combine js halves in LDS, normalize, residual, elu
        float* ep  = (float*)&frag[0][0][0][0];      // 16 KB scratch (dead)
        float* zep = (float*)&frag[1][0][0][0];      // 256 B scratch (dead)
#pragma unroll
        for (int q = 0; q < 4; ++q) {
            int rloc = rr * 16 + 4 * ag + q;
            ep[(js * 32 + rloc) * 64 +  0 + am] = acc0[q];
            ep[(js * 32 + rloc) * 64 + 16 + am] = acc1[q];
            ep[(js * 32 + rloc) * 64 + 32 + am] = acc2[q];
            ep[(js * 32 + rloc) * 64 + 48 + am] = acc3[q];
            if (am == 0) zep[js * 32 + rloc] = accz[q];
        }
        __syncthreads();

        int rl = t >> 3, fo = (t & 7) * 8;           // 32 rows x 8 f-octets
        float zinv = 1.f / (zep[rl] + zep[32 + rl]);
        size_t base = ((size_t)(b * Nn + bx * 32 + rl)) * 64 + fo;
        const float* e0p = &ep[rl * 64 + fo];
        const float* e1p = &ep[(32 + rl) * 64 + fo];
        float4 h0 = *(const float4*)&h[base];
        float4 h1 = *(const float4*)&h[base + 4];
        float4 o0, o1;
        o0.x = (e0p[0] + e1p[0]) * zinv + h0.x; o0.x = o0.x > 0.f ? o0.x : expm1f(o0.x);
        o0.y = (e0p[1] + e1p[1]) * zinv + h0.y; o0.y = o0.y > 0.f ? o0.y : expm1f(o0.y);
        o0.z = (e0p[2] + e1p[2]) * zinv + h0.z; o0.z = o0.z > 0.f ? o0.z : expm1f(o0.z);
        o0.w = (e0p[3] + e1p[3]) * zinv + h0.w; o0.w = o0.w > 0.f ? o0.w : expm1f(o0.w);
        o1.x = (e0p[4] + e1p[4]) * zinv + h1.x; o1.x = o1.x > 0.f ? o1.x : expm1f(o1.x);
        o1.y = (e0p[5] + e1p[5]) * zinv + h1.y; o1.y = o1.y > 0.f ? o1.y : expm1f(o1.y);
        o1.z = (e0p[6] + e1p[6]) * zinv + h1.z; o1.z = o1.z > 0.f ? o1.z : expm1f(o1.z);
        o1.w = (e0p[7] + e1p[7]) * zinv + h1.w; o1.w = o1.w > 0.f ? o1.w : expm1f(o1.w);
        *(float4*)&out[base] = o0;
        *(float4*)&out[base + 4] = o1;
    }
}

// ---------------- launch ----------------
extern "C" void kernel_launch(void* const* d_in, const int* in_sizes, int n_in,
                              void* d_out, int out_size, void* d_ws, size_t ws_size,
                              hipStream_t stream) {
    const float* in  = (const float*)d_in[0];
    const int*   adj = (const int*)d_in[1];
    const float* W   = (const float*)d_in[2];
    const float* a   = (const float*)d_in[3];
    const float* nw  = (const float*)d_in[4];
    const float* nb  = (const float*)d_in[5];
    const float* gam = (const float*)d_in[6];
    const float* bet = (const float*)d_in[7];
    float* out = (float*)d_out;

    char* ws = (char*)d_ws;
    float* h   = (float*)ws;                                       // 4 MB
    float* s1L = (float*)(ws + (size_t)Bb * Nn * 64 * 4);          // 64 KB
    float* s2L = s1L + (size_t)Bb * Nn;                            // 64 KB
    unsigned int* bitsT = (unsigned int*)(s2L + (size_t)Bb * Nn);  // 512 KB
    unsigned short* hT2 = (unsigned short*)(bitsT + (size_t)Nn * Nn / 32); // 2 MB

    hipLaunchKernelGGL((prep<10>), dim3(Nn + Bb * Nn / 64), dim3(256), 0, stream,
                       adj, in, W, a, nw, nb, gam, bet, bitsT, h, s1L, s2L, hT2);
    hipLaunchKernelGGL((attention9<6>), dim3(Nn / 32, Bb), dim3(256), 0, stream,
                       h, hT2, s1L, s2L, bitsT, out);
}

// Round 17
// 28.846 us; speedup vs baseline: 3.6286x; 3.6286x over previous
//
#include <hip/hip_runtime.h>
#include <math.h>

#define Bb 8
#define Nn 2048
#define ALPHA 0.2f
#define LN_EPS 1e-5f
#define LOG2E 1.4426950408889634f

typedef __attribute__((ext_vector_type(8))) short short8;
typedef __attribute__((ext_vector_type(4))) float f32x4;
typedef __attribute__((ext_vector_type(4))) int int4v;

__device__ inline unsigned short f2bf(float f) {
    unsigned u = __builtin_bit_cast(unsigned, f);
    u += 0x7fffu + ((u >> 16) & 1u);   // RNE
    return (unsigned short)(u >> 16);
}

__device__ __forceinline__ void gll16(const void* g, void* l) {
    __builtin_amdgcn_global_load_lds(
        (const __attribute__((address_space(1))) unsigned int*)g,
        (__attribute__((address_space(3))) unsigned int*)l, 16, 0, 0);
}

// ---- Kernel 1: PREP = pack_mask (blocks 0..2047) + node_transform_mfma ----
// nt blocks XCD-remapped: k=bid-Nn -> batch b=k&7 (XCD b), chunk c=k>>3.
__global__ __launch_bounds__(256) void prep(
    const int* __restrict__ adj,
    const float* __restrict__ in, const float* __restrict__ W,
    const float* __restrict__ a, const float* __restrict__ nw,
    const float* __restrict__ nb, const float* __restrict__ gam,
    const float* __restrict__ bet,
    unsigned int* __restrict__ bitsT,
    float* __restrict__ h, float* __restrict__ s1L, float* __restrict__ s2L,
    unsigned short* __restrict__ hT2)
{
    __shared__ unsigned char rowb[256];
    int bid = blockIdx.x, t = threadIdx.x;

    if (bid < Nn) {
        int i = bid;
        const int4* arow = (const int4*)(adj + (size_t)i * Nn);
        int4 v0 = arow[t * 2], v1 = arow[t * 2 + 1];
        unsigned by = (unsigned)(v0.x > 0)       | ((unsigned)(v0.y > 0) << 1)
                    | ((unsigned)(v0.z > 0) << 2) | ((unsigned)(v0.w > 0) << 3)
                    | ((unsigned)(v1.x > 0) << 4) | ((unsigned)(v1.y > 0) << 5)
                    | ((unsigned)(v1.z > 0) << 6) | ((unsigned)(v1.w > 0) << 7);
        rowb[t] = (unsigned char)by;
        __syncthreads();
        if (t < 64) {
            unsigned w32;
            __builtin_memcpy(&w32, &rowb[t * 4], 4);
            bitsT[((size_t)(i >> 4) * 64 + t) * 16 + (i & 15)] = w32;
        }
        return;
    }

    int lane = t & 63, wv = t >> 6;
    int am = lane & 15, ag = lane >> 4;
    int k = bid - Nn;
    int b = k & 7, c = k >> 3;                       // XCD-local batch decode
    int node0 = b * Nn + c * 64 + wv * 16;
    int n0 = node0 & (Nn - 1);

    short8 wf[4][2];
#pragma unroll
    for (int cb = 0; cb < 4; ++cb)
#pragma unroll
        for (int kh = 0; kh < 2; ++kh)
#pragma unroll
            for (int e = 0; e < 8; ++e)
                wf[cb][kh][e] = (short)f2bf(W[(kh * 32 + 8 * ag + e) * 64 + cb * 16 + am]);

    int nrow = n0 + am;
    float nwv = nw[nrow] + 1.0f, nbv = nb[nrow];
    const float* xrow = in + (size_t)(node0 + am) * 64 + 8 * ag;
    short8 xa0, xa1;
#pragma unroll
    for (int e = 0; e < 8; ++e) {
        xa0[e] = (short)f2bf(xrow[e] * nwv + nbv);
        xa1[e] = (short)f2bf(xrow[32 + e] * nwv + nbv);
    }

    f32x4 acc0 = {0,0,0,0}, acc1 = {0,0,0,0}, acc2 = {0,0,0,0}, acc3 = {0,0,0,0};
    acc0 = __builtin_amdgcn_mfma_f32_16x16x32_bf16(xa0, wf[0][0], acc0, 0, 0, 0);
    acc1 = __builtin_amdgcn_mfma_f32_16x16x32_bf16(xa0, wf[1][0], acc1, 0, 0, 0);
    acc2 = __builtin_amdgcn_mfma_f32_16x16x32_bf16(xa0, wf[2][0], acc2, 0, 0, 0);
    acc3 = __builtin_amdgcn_mfma_f32_16x16x32_bf16(xa0, wf[3][0], acc3, 0, 0, 0);
    acc0 = __builtin_amdgcn_mfma_f32_16x16x32_bf16(xa1, wf[0][1], acc0, 0, 0, 0);
    acc1 = __builtin_amdgcn_mfma_f32_16x16x32_bf16(xa1, wf[1][1], acc1, 0, 0, 0);
    acc2 = __builtin_amdgcn_mfma_f32_16x16x32_bf16(xa1, wf[2][1], acc2, 0, 0, 0);
    acc3 = __builtin_amdgcn_mfma_f32_16x16x32_bf16(xa1, wf[3][1], acc3, 0, 0, 0);

    float mu[4], rsq[4];
#pragma unroll
    for (int q = 0; q < 4; ++q) {
        float s = (acc0[q] + acc1[q]) + (acc2[q] + acc3[q]);
        s += __shfl_xor(s, 1, 64); s += __shfl_xor(s, 2, 64);
        s += __shfl_xor(s, 4, 64); s += __shfl_xor(s, 8, 64);
        mu[q] = s * (1.f / 64.f);
    }
#pragma unroll
    for (int q = 0; q < 4; ++q) {
        float d0 = acc0[q] - mu[q], d1 = acc1[q] - mu[q];
        float d2 = acc2[q] - mu[q], d3 = acc3[q] - mu[q];
        float ss = (d0 * d0 + d1 * d1) + (d2 * d2 + d3 * d3);
        ss += __shfl_xor(ss, 1, 64); ss += __shfl_xor(ss, 2, 64);
        ss += __shfl_xor(ss, 4, 64); ss += __shfl_xor(ss, 8, 64);
        rsq[q] = rsqrtf(ss * (1.f / 64.f) + LN_EPS);
    }
    float gl0 = gam[am], gl1 = gam[16 + am], gl2 = gam[32 + am], gl3 = gam[48 + am];
    float bl0 = bet[am], bl1 = bet[16 + am], bl2 = bet[32 + am], bl3 = bet[48 + am];
    f32x4 hn0, hn1, hn2, hn3;
#pragma unroll
    for (int q = 0; q < 4; ++q) {
        hn0[q] = (acc0[q] - mu[q]) * rsq[q] * gl0 + bl0;
        hn1[q] = (acc1[q] - mu[q]) * rsq[q] * gl1 + bl1;
        hn2[q] = (acc2[q] - mu[q]) * rsq[q] * gl2 + bl2;
        hn3[q] = (acc3[q] - mu[q]) * rsq[q] * gl3 + bl3;
    }

    float a10 = a[am], a11 = a[16 + am], a12 = a[32 + am], a13 = a[48 + am];
    float a20 = a[64 + am], a21 = a[80 + am], a22 = a[96 + am], a23 = a[112 + am];
    float s1p[4], s2p[4];
#pragma unroll
    for (int q = 0; q < 4; ++q) {
        float s1v = (hn0[q] * a10 + hn1[q] * a11) + (hn2[q] * a12 + hn3[q] * a13);
        float s2v = (hn0[q] * a20 + hn1[q] * a21) + (hn2[q] * a22 + hn3[q] * a23);
        s1v += __shfl_xor(s1v, 1, 64); s1v += __shfl_xor(s1v, 2, 64);
        s1v += __shfl_xor(s1v, 4, 64); s1v += __shfl_xor(s1v, 8, 64);
        s2v += __shfl_xor(s2v, 1, 64); s2v += __shfl_xor(s2v, 2, 64);
        s2v += __shfl_xor(s2v, 4, 64); s2v += __shfl_xor(s2v, 8, 64);
        s1p[q] = s1v; s2p[q] = s2v;
    }
    if (am == 0) {
#pragma unroll
        for (int q = 0; q < 4; ++q) {
            s1L[node0 + ag * 4 + q] = s1p[q] * LOG2E;
            s2L[node0 + ag * 4 + q] = s2p[q] * LOG2E;
        }
    }

#pragma unroll
    for (int q = 0; q < 4; ++q) {
        float* hp = h + (size_t)(node0 + ag * 4 + q) * 64 + am;
        hp[0] = hn0[q]; hp[16] = hn1[q]; hp[32] = hn2[q]; hp[48] = hn3[q];
    }

    int jw = n0 >> 5;
    int AG2 = ((n0 & 31) >> 3) + (ag >> 1);
    int e0 = (ag & 1) * 4;
    size_t fbase = ((size_t)((b * 64 + jw) * 4)) * 512 + (AG2 * 16 + am) * 8 + e0;
#pragma unroll
    for (int cb = 0; cb < 4; ++cb) {
        f32x4 hc = cb == 0 ? hn0 : cb == 1 ? hn1 : cb == 2 ? hn2 : hn3;
        unsigned short v[4] = {f2bf(hc[0]), f2bf(hc[1]), f2bf(hc[2]), f2bf(hc[3])};
        *(uint2*)&hT2[fbase + (size_t)cb * 512] = *(uint2*)v;
    }
}

// ---- Kernel 2: full-j attention, factorized exp, XCD-local decode ----------
// grid 512 linear: b = id&7 (-> XCD b), bx = id>>3. 4 waves: rr=wv&1, js=wv>>1.
// p = max(E1p*E2p, E1n*E2n)  [exp2 monotone + leaky = max(x, 0.2x)] — exact.
__global__ __launch_bounds__(256) void attention9(
    const float* __restrict__ h, const unsigned short* __restrict__ hT2,
    const float* __restrict__ s1L, const float* __restrict__ s2L,
    const unsigned int* __restrict__ bitsT, float* __restrict__ out)
{
    __shared__ __align__(16) unsigned short frag[2][4][4][512];  // 32 KB ring
    __shared__ __align__(16) unsigned int mask_lds[2][64][16];   // 8 KB
    __shared__ __align__(16) float s2l[2048];                    // 8 KB
    __shared__ __align__(16) float s2e[2048 * 2];                // 16 KB E2 pairs

    int t = threadIdx.x, wv = t >> 6, lane = t & 63;
    int am = lane & 15, ag = lane >> 4;
    int rr = wv & 1, js = wv >> 1;
    int id = blockIdx.x;
    int b = id & 7, bx = id >> 3;

    float s1r = s1L[b * Nn + bx * 32 + rr * 16 + am];
    float E1p = __builtin_amdgcn_exp2f(s1r);
    float E1n = __builtin_amdgcn_exp2f(0.2f * s1r);
    const unsigned int* msrc = bitsT + (size_t)(bx * 2) * 1024;
    const float* ssrc = s2L + b * Nn;
    const unsigned short* slab = hT2 + (size_t)b * 131072;

    // stage mask + s2, and stage-0 frags
#pragma unroll
    for (int k = 0; k < 2; ++k) {
        int sl = wv * 2 + k;
        gll16(msrc + sl * 256 + lane * 4, &((unsigned int*)mask_lds)[sl * 256]);
        gll16(ssrc + sl * 256 + lane * 4, &s2l[sl * 256]);
    }
#pragma unroll
    for (int fb = 0; fb < 4; ++fb)
        gll16(slab + (size_t)(wv * 4 + fb) * 512 + lane * 8, &frag[0][wv][fb][0]);
    asm volatile("s_waitcnt vmcnt(0)" ::: "memory");
    __builtin_amdgcn_s_barrier();

    // build E2 table: 8 j per thread (O(N) exps replace O(N^2))
#pragma unroll
    for (int k = 0; k < 8; ++k) {
        int j = t * 8 + k;
        float v = s2l[j];
        s2e[j * 2]     = __builtin_amdgcn_exp2f(v);
        s2e[j * 2 + 1] = __builtin_amdgcn_exp2f(0.2f * v);
    }
    __syncthreads();

    f32x4 acc0 = {0,0,0,0}, acc1 = {0,0,0,0}, acc2 = {0,0,0,0}, acc3 = {0,0,0,0};
    f32x4 accz = {0,0,0,0};
    const short8 vone = {(short)0x3F80, (short)0x3F80, (short)0x3F80, (short)0x3F80,
                         (short)0x3F80, (short)0x3F80, (short)0x3F80, (short)0x3F80};

#pragma unroll
    for (int st = 0; st < 16; ++st) {
        if (st < 15) {                                   // prefetch next stage
            int gw = (st + 1) * 4 + wv;
#pragma unroll
            for (int fb = 0; fb < 4; ++fb)
                gll16(slab + (size_t)(gw * 4 + fb) * 512 + lane * 8,
                      &frag[(st + 1) & 1][wv][fb][0]);
        }
#pragma unroll
        for (int wi = 0; wi < 2; ++wi) {
            int wls = js * 2 + wi;                       // stage-local word
            int wl = st * 4 + wls;                       // global word
            unsigned wd = mask_lds[rr][wl][am];
            const float* qb = &s2e[(wl * 32 + 8 * ag) * 2];
            float4 q0 = *(const float4*)&qb[0];
            float4 q1 = *(const float4*)&qb[4];
            float4 q2 = *(const float4*)&qb[8];
            float4 q3 = *(const float4*)&qb[12];
            float p[8];
            p[0] = fmaxf(E1p * q0.x, E1n * q0.y);
            p[1] = fmaxf(E1p * q0.z, E1n * q0.w);
            p[2] = fmaxf(E1p * q1.x, E1n * q1.y);
            p[3] = fmaxf(E1p * q1.z, E1n * q1.w);
            p[4] = fmaxf(E1p * q2.x, E1n * q2.y);
            p[5] = fmaxf(E1p * q2.z, E1n * q2.w);
            p[6] = fmaxf(E1p * q3.x, E1n * q3.y);
            p[7] = fmaxf(E1p * q3.z, E1n * q3.w);
#pragma unroll
            for (int e = 0; e < 8; ++e)
                p[e] = ((wd >> (8 * ag + e)) & 1u) ? p[e] : 0.f;
            int4v aw;
            aw.x = __builtin_amdgcn_perm(__builtin_bit_cast(unsigned, p[1]),
                                         __builtin_bit_cast(unsigned, p[0]), 0x07060302u);
            aw.y = __builtin_amdgcn_perm(__builtin_bit_cast(unsigned, p[3]),
                                         __builtin_bit_cast(unsigned, p[2]), 0x07060302u);
            aw.z = __builtin_amdgcn_perm(__builtin_bit_cast(unsigned, p[5]),
                                         __builtin_bit_cast(unsigned, p[4]), 0x07060302u);
            aw.w = __builtin_amdgcn_perm(__builtin_bit_cast(unsigned, p[7]),
                                         __builtin_bit_cast(unsigned, p[6]), 0x07060302u);
            short8 af = __builtin_bit_cast(short8, aw);
            short8 f0 = *(const short8*)&frag[st & 1][wls][0][lane * 8];
            short8 f1 = *(const short8*)&frag[st & 1][wls][1][lane * 8];
            short8 f2 = *(const short8*)&frag[st & 1][wls][2][lane * 8];
            short8 f3 = *(const short8*)&frag[st & 1][wls][3][lane * 8];
            acc0 = __builtin_amdgcn_mfma_f32_16x16x32_bf16(af, f0, acc0, 0, 0, 0);
            acc1 = __builtin_amdgcn_mfma_f32_16x16x32_bf16(af, f1, acc1, 0, 0, 0);
            acc2 = __builtin_amdgcn_mfma_f32_16x16x32_bf16(af, f2, acc2, 0, 0, 0);
            acc3 = __builtin_amdgcn_mfma_f32_16x16x32_bf16(af, f3, acc3, 0, 0, 0);
            accz = __builtin_amdgcn_mfma_f32_16x16x32_bf16(af, vone, accz, 0, 0, 0);
        }
        asm volatile("s_waitcnt vmcnt(0)" ::: "memory");
        __builtin_amdgcn_s_barrier();
    }

    // ---- epilogue: combine js halves in LDS, normalize, residual, elu ----
    float* ep  = (float*)&frag[0][0][0][0];      // 16 KB scratch (dead)
    float* zep = (float*)&frag[1][0][0][0];      // 256 B scratch (dead)
#pragma unroll
    for (int q = 0; q < 4; ++q) {
        int rloc = rr * 16 + 4 * ag + q;
        ep[(js * 32 + rloc) * 64 +  0 + am] = acc0[q];
        ep[(js * 32 + rloc) * 64 + 16 + am] = acc1[q];
        ep[(js * 32 + rloc) * 64 + 32 + am] = acc2[q];
        ep[(js * 32 + rloc) * 64 + 48 + am] = acc3[q];
        if (am == 0) zep[js * 32 + rloc] = accz[q];
    }
    __syncthreads();

    int rl = t >> 3, fo = (t & 7) * 8;           // 32 rows x 8 f-octets
    float zinv = 1.f / (zep[rl] + zep[32 + rl]);
    size_t base = ((size_t)(b * Nn + bx * 32 + rl)) * 64 + fo;
    const float* e0p = &ep[rl * 64 + fo];
    const float* e1p = &ep[(32 + rl) * 64 + fo];
    float4 h0 = *(const float4*)&h[base];
    float4 h1 = *(const float4*)&h[base + 4];
    float4 o0, o1;
    o0.x = (e0p[0] + e1p[0]) * zinv + h0.x; o0.x = o0.x > 0.f ? o0.x : expm1f(o0.x);
    o0.y = (e0p[1] + e1p[1]) * zinv + h0.y; o0.y = o0.y > 0.f ? o0.y : expm1f(o0.y);
    o0.z = (e0p[2] + e1p[2]) * zinv + h0.z; o0.z = o0.z > 0.f ? o0.z : expm1f(o0.z);
    o0.w = (e0p[3] + e1p[3]) * zinv + h0.w; o0.w = o0.w > 0.f ? o0.w : expm1f(o0.w);
    o1.x = (e0p[4] + e1p[4]) * zinv + h1.x; o1.x = o1.x > 0.f ? o1.x : expm1f(o1.x);
    o1.y = (e0p[5] + e1p[5]) * zinv + h1.y; o1.y = o1.y > 0.f ? o1.y : expm1f(o1.y);
    o1.z = (e0p[6] + e1p[6]) * zinv + h1.z; o1.z = o1.z > 0.f ? o1.z : expm1f(o1.z);
    o1.w = (e0p[7] + e1p[7]) * zinv + h1.w; o1.w = o1.w > 0.f ? o1.w : expm1f(o1.w);
    *(float4*)&out[base] = o0;
    *(float4*)&out[base + 4] = o1;
}

// ---------------- launch ----------------
extern "C" void kernel_launch(void* const* d_in, const int* in_sizes, int n_in,
                              void* d_out, int out_size, void* d_ws, size_t ws_size,
                              hipStream_t stream) {
    const float* in  = (const float*)d_in[0];
    const int*   adj = (const int*)d_in[1];
    const float* W   = (const float*)d_in[2];
    const float* a   = (const float*)d_in[3];
    const float* nw  = (const float*)d_in[4];
    const float* nb  = (const float*)d_in[5];
    const float* gam = (const float*)d_in[6];
    const float* bet = (const float*)d_in[7];
    float* out = (float*)d_out;

    char* ws = (char*)d_ws;
    float* h   = (float*)ws;                                       // 4 MB
    float* s1L = (float*)(ws + (size_t)Bb * Nn * 64 * 4);          // 64 KB
    float* s2L = s1L + (size_t)Bb * Nn;                            // 64 KB
    unsigned int* bitsT = (unsigned int*)(s2L + (size_t)Bb * Nn);  // 512 KB
    unsigned short* hT2 = (unsigned short*)(bitsT + (size_t)Nn * Nn / 32); // 2 MB

    hipLaunchKernelGGL(prep, dim3(Nn + Bb * Nn / 64), dim3(256), 0, stream,
                       adj, in, W, a, nw, nb, gam, bet, bitsT, h, s1L, s2L, hT2);
    hipLaunchKernelGGL(attention9, dim3(512), dim3(256), 0, stream,
                       h, hT2, s1L, s2L, bitsT, out);
}